// Round 1
// baseline (12934.334 us; speedup 1.0000x reference)
//
#include <hip/hip_runtime.h>

// HSN layer: out = sigmoid( A0 @ (sig(A0 @ (x W1_00)) W2_00) + B1 @ (sig(B1^T @ (x W1_01)) W2_10) )
// Feature dim C = 128 (fixed).

#define CF 128

// ---------------------------------------------------------------------------
// GEMM: Y[M x 128] = X[M x 128] @ W[128 x 128], f32.
// 128-row x 128-col tile per 256-thread block; each thread owns an 8x8
// micro-tile. No LDS: X/W fragments come through L1 (heavy same-address
// broadcast: W shared by all blocks, each X row shared by 16 threads).
// ---------------------------------------------------------------------------
__global__ __launch_bounds__(256)
void gemm128(const float* __restrict__ X, const float* __restrict__ W,
             float* __restrict__ Y, int M) {
  const int tid = threadIdx.x;
  const int row0 = blockIdx.x * 128;
  const int rbase = row0 + ((tid & 15) << 3);   // first of this thread's 8 rows
  const int c0 = (tid >> 4) << 3;               // first of this thread's 8 cols

  // Clamp OOB rows for loads (garbage is computed but never stored).
  size_t rowx[8];
#pragma unroll
  for (int i = 0; i < 8; ++i) {
    int r = rbase + i;
    rowx[i] = (size_t)((r < M) ? r : (M - 1)) * (CF / 4);
  }

  const float4* X4 = (const float4*)X;
  const float4* W4 = (const float4*)W;

  float acc[8][8];
#pragma unroll
  for (int i = 0; i < 8; ++i)
#pragma unroll
    for (int j = 0; j < 8; ++j) acc[i][j] = 0.f;

  for (int kq = 0; kq < 32; ++kq) {   // 32 quads of k => K=128
    float4 xv[8];
#pragma unroll
    for (int i = 0; i < 8; ++i) xv[i] = X4[rowx[i] + kq];

#pragma unroll
    for (int j = 0; j < 4; ++j) {
      const int k = (kq << 2) + j;
      const float4 wa = W4[(size_t)k * (CF / 4) + (c0 >> 2)];
      const float4 wb = W4[(size_t)k * (CF / 4) + (c0 >> 2) + 1];
#pragma unroll
      for (int i = 0; i < 8; ++i) {
        const float xk = (j == 0) ? xv[i].x
                       : (j == 1) ? xv[i].y
                       : (j == 2) ? xv[i].z : xv[i].w;
        acc[i][0] += xk * wa.x;
        acc[i][1] += xk * wa.y;
        acc[i][2] += xk * wa.z;
        acc[i][3] += xk * wa.w;
        acc[i][4] += xk * wb.x;
        acc[i][5] += xk * wb.y;
        acc[i][6] += xk * wb.z;
        acc[i][7] += xk * wb.w;
      }
    }
  }

#pragma unroll
  for (int i = 0; i < 8; ++i) {
    const int r = rbase + i;
    if (r < M) {
      float4* Yp = (float4*)(Y + (size_t)r * CF + c0);
      Yp[0] = make_float4(acc[i][0], acc[i][1], acc[i][2], acc[i][3]);
      Yp[1] = make_float4(acc[i][4], acc[i][5], acc[i][6], acc[i][7]);
    }
  }
}

// ---------------------------------------------------------------------------
// COO SpMM scatter: out[rows[e], :] += vals[e] * xin[cols[e], :]
// One half-wave (32 lanes) per nnz; float4 per lane covers the 128 features.
// f32 atomics (device scope) into a zero-initialized accumulator.
// ---------------------------------------------------------------------------
__global__ __launch_bounds__(256)
void spmm_atomic(const int* __restrict__ rows, const int* __restrict__ cols,
                 const float* __restrict__ vals, const float* __restrict__ xin,
                 float* __restrict__ out, int nnz) {
  const int tid = threadIdx.x;
  const int sub = tid >> 5;        // 0..7: half-wave id within block
  const int l32 = tid & 31;
  const long long e = (long long)blockIdx.x * 8 + sub;
  if (e >= nnz) return;

  const int r = rows[e];
  const int c = cols[e];
  const float v = vals[e];

  const float4 xv = ((const float4*)(xin + (size_t)c * CF))[l32];
  float* o = out + (size_t)r * CF + (l32 << 2);
  atomicAdd(o + 0, v * xv.x);
  atomicAdd(o + 1, v * xv.y);
  atomicAdd(o + 2, v * xv.z);
  atomicAdd(o + 3, v * xv.w);
}

// ---------------------------------------------------------------------------
// In-place sigmoid over n4 float4's.
// ---------------------------------------------------------------------------
__global__ __launch_bounds__(256)
void sigmoid_k(float* __restrict__ x, int n4) {
  const int i = blockIdx.x * 256 + threadIdx.x;
  if (i < n4) {
    float4 v = ((float4*)x)[i];
    v.x = 1.f / (1.f + __expf(-v.x));
    v.y = 1.f / (1.f + __expf(-v.y));
    v.z = 1.f / (1.f + __expf(-v.z));
    v.w = 1.f / (1.f + __expf(-v.w));
    ((float4*)x)[i] = v;
  }
}

extern "C" void kernel_launch(void* const* d_in, const int* in_sizes, int n_in,
                              void* d_out, int out_size, void* d_ws, size_t ws_size,
                              hipStream_t stream) {
  const float* x      = (const float*)d_in[0];
  const float* W1_00  = (const float*)d_in[1];
  const float* W1_01  = (const float*)d_in[2];
  const float* W2_00  = (const float*)d_in[3];
  const float* W2_10  = (const float*)d_in[4];
  const int*   adj_rows = (const int*)d_in[5];
  const int*   adj_cols = (const int*)d_in[6];
  const float* adj_vals = (const float*)d_in[7];
  const int*   inc_rows = (const int*)d_in[8];
  const int*   inc_cols = (const int*)d_in[9];
  const float* inc_vals = (const float*)d_in[10];

  const int adj_nnz = in_sizes[5];             // 3,200,000
  const int inc_nnz = in_sizes[8];             // 400,000
  const int n_nodes = in_sizes[0] / CF;        // 100,000
  const int n_edges = 200000;                  // problem constant (not in in_sizes)

  const long long NE = (long long)n_nodes * CF;   // 12.8M floats
  const long long EE = (long long)n_edges * CF;   // 25.6M floats

  // Workspace layout (liveness-packed), 64M floats = 256 MB total:
  //   [0, NE)            tA : t2 = x@W1_01, later t3 = n1@W2_00
  //   [NE, NE+EE)        e1 : edge-level accumulator / activations
  //   [NE+EE, NE+EE+2NE) n1 (first NE) then reused as t4 (full 2NE = EE)
  float* wsf = (float*)d_ws;
  float* tA = wsf;
  float* e1 = wsf + NE;
  float* n1 = wsf + NE + EE;
  float* t4 = n1;                 // reuses n1's region + the tail region
  float* t1 = (float*)d_out;      // d_out doubles as t1 until re-zeroed
  float* outf = (float*)d_out;

  const dim3 blk(256);
  const int gemm_gn = (n_nodes + 127) / 128;
  const int gemm_ge = (n_edges + 127) / 128;

  // Level 1 GEMMs
  gemm128<<<gemm_gn, blk, 0, stream>>>(x, W1_00, t1, n_nodes);
  gemm128<<<gemm_gn, blk, 0, stream>>>(x, W1_01, tA, n_nodes);

  // Zero accumulators (ws is poisoned 0xAA before every launch)
  hipMemsetAsync(n1, 0, NE * sizeof(float), stream);
  hipMemsetAsync(e1, 0, EE * sizeof(float), stream);

  // Level 1 SpMMs
  // x_nodes_l1 acc: n1[adj_rows[e]] += adj_vals[e] * t1[adj_cols[e]]
  spmm_atomic<<<(adj_nnz + 7) / 8, blk, 0, stream>>>(adj_rows, adj_cols, adj_vals, t1, n1, adj_nnz);
  // x_edges_l1 acc: e1[inc_cols[e]] += inc_vals[e] * tA[inc_rows[e]]   (B1^T)
  spmm_atomic<<<(inc_nnz + 7) / 8, blk, 0, stream>>>(inc_cols, inc_rows, inc_vals, tA, e1, inc_nnz);

  // Sigmoid updates
  sigmoid_k<<<(int)((NE / 4 + 255) / 256), blk, 0, stream>>>(n1, (int)(NE / 4));
  sigmoid_k<<<(int)((EE / 4 + 255) / 256), blk, 0, stream>>>(e1, (int)(EE / 4));

  // Level 2 GEMMs (tA freed -> t3; n1 consumed then overwritten by t4)
  gemm128<<<gemm_gn, blk, 0, stream>>>(n1, W2_00, tA, n_nodes);
  gemm128<<<gemm_ge, blk, 0, stream>>>(e1, W2_10, t4, n_edges);

  // Final accumulation into d_out (t1 is dead now)
  hipMemsetAsync(outf, 0, NE * sizeof(float), stream);
  // x_nodes_l2: out[adj_rows[e]] += adj_vals[e] * t3[adj_cols[e]]
  spmm_atomic<<<(adj_nnz + 7) / 8, blk, 0, stream>>>(adj_rows, adj_cols, adj_vals, tA, outf, adj_nnz);
  // x_edges_l2: out[inc_rows[e]] += inc_vals[e] * t4[inc_cols[e]]   (B1)
  spmm_atomic<<<(inc_nnz + 7) / 8, blk, 0, stream>>>(inc_rows, inc_cols, inc_vals, t4, outf, inc_nnz);

  // Merge sigmoid
  sigmoid_k<<<(int)((NE / 4 + 255) / 256), blk, 0, stream>>>(outf, (int)(NE / 4));
}

// Round 2
// 1814.376 us; speedup vs baseline: 7.1288x; 7.1288x over previous
//
#include <hip/hip_runtime.h>

// HSN layer: out = sigmoid( A0 @ (sig(A0 @ (x W1_00)) W2_00) + B1 @ (sig(B1^T @ (x W1_01)) W2_10) )
// C = 128 fixed. Strategy: on-device CSR build (hist/scan/scatter), then
// gather-SpMM one-wave-per-row with fused sigmoid epilogues. No f32 atomics.

#define CF 128

// ---------------------------------------------------------------------------
// GEMM: Y[M x 128] = X[M x 128] @ W[128 x 128], f32. 128x128 tile / 8x8
// micro-tile. __syncthreads before stores => safe for Y == X (in-place),
// since each block reads exactly the rows it writes.
// ---------------------------------------------------------------------------
__global__ __launch_bounds__(256)
void gemm128(const float* X, const float* W, float* Y, int M) {
  const int tid = threadIdx.x;
  const int row0 = blockIdx.x * 128;
  const int rbase = row0 + ((tid & 15) << 3);
  const int c0 = (tid >> 4) << 3;

  size_t rowx[8];
#pragma unroll
  for (int i = 0; i < 8; ++i) {
    int r = rbase + i;
    rowx[i] = (size_t)((r < M) ? r : (M - 1)) * (CF / 4);
  }

  const float4* X4 = (const float4*)X;
  const float4* W4 = (const float4*)W;

  float acc[8][8];
#pragma unroll
  for (int i = 0; i < 8; ++i)
#pragma unroll
    for (int j = 0; j < 8; ++j) acc[i][j] = 0.f;

  for (int kq = 0; kq < 32; ++kq) {
    float4 xv[8];
#pragma unroll
    for (int i = 0; i < 8; ++i) xv[i] = X4[rowx[i] + kq];

#pragma unroll
    for (int j = 0; j < 4; ++j) {
      const int k = (kq << 2) + j;
      const float4 wa = W4[(size_t)k * (CF / 4) + (c0 >> 2)];
      const float4 wb = W4[(size_t)k * (CF / 4) + (c0 >> 2) + 1];
#pragma unroll
      for (int i = 0; i < 8; ++i) {
        const float xk = (j == 0) ? xv[i].x
                       : (j == 1) ? xv[i].y
                       : (j == 2) ? xv[i].z : xv[i].w;
        acc[i][0] += xk * wa.x;  acc[i][1] += xk * wa.y;
        acc[i][2] += xk * wa.z;  acc[i][3] += xk * wa.w;
        acc[i][4] += xk * wb.x;  acc[i][5] += xk * wb.y;
        acc[i][6] += xk * wb.z;  acc[i][7] += xk * wb.w;
      }
    }
  }

  __syncthreads();   // all reads of this block's X rows done -> in-place safe

#pragma unroll
  for (int i = 0; i < 8; ++i) {
    const int r = rbase + i;
    if (r < M) {
      float4* Yp = (float4*)(Y + (size_t)r * CF + c0);
      Yp[0] = make_float4(acc[i][0], acc[i][1], acc[i][2], acc[i][3]);
      Yp[1] = make_float4(acc[i][4], acc[i][5], acc[i][6], acc[i][7]);
    }
  }
}

// --------------------------- CSR build kernels -----------------------------
__global__ __launch_bounds__(256)
void hist_k(const int* __restrict__ rows, int* __restrict__ cnt, int nnz) {
  int i = blockIdx.x * 256 + threadIdx.x;
  if (i < nnz) atomicAdd(&cnt[rows[i]], 1);
}

// exclusive scan, 1024 elements per block (256 thr x 4), emits block sums
__global__ __launch_bounds__(256)
void scan_block(const int* __restrict__ cnt, int* __restrict__ ptr,
                int* __restrict__ blksum, int n) {
  __shared__ int sdata[256];
  const int t = threadIdx.x;
  const int idx = blockIdx.x * 1024 + t * 4;
  int v[4];
#pragma unroll
  for (int k = 0; k < 4; ++k) v[k] = (idx + k < n) ? cnt[idx + k] : 0;
  int tsum = v[0] + v[1] + v[2] + v[3];
  sdata[t] = tsum;
  __syncthreads();
  for (int off = 1; off < 256; off <<= 1) {
    int x = (t >= off) ? sdata[t - off] : 0;
    __syncthreads();
    sdata[t] += x;
    __syncthreads();
  }
  if (t == 255) blksum[blockIdx.x] = sdata[255];
  int run = sdata[t] - tsum;   // exclusive prefix of this thread's chunk
#pragma unroll
  for (int k = 0; k < 4; ++k) {
    if (idx + k < n) ptr[idx + k] = run;
    run += v[k];
  }
}

// serial exclusive scan of block sums (nb <= 1024, actually <= ~200)
__global__ void scan_sums(int* blksum, int nb) {
  if (threadIdx.x == 0) {
    int run = 0;
    for (int i = 0; i < nb; ++i) { int c = blksum[i]; blksum[i] = run; run += c; }
  }
}

__global__ __launch_bounds__(256)
void scan_add(int* __restrict__ ptr, int* __restrict__ cursor,
              const int* __restrict__ blkoff, int n) {
  const int off = blkoff[blockIdx.x];
  const int base = blockIdx.x * 1024 + threadIdx.x;
#pragma unroll
  for (int k = 0; k < 4; ++k) {
    int i = base + k * 256;
    if (i < n) { int v = ptr[i] + off; ptr[i] = v; cursor[i] = v; }
  }
}

__global__ __launch_bounds__(256)
void scatter_k(const int* __restrict__ rows, const int* __restrict__ cols,
               const float* __restrict__ vals, int* __restrict__ cursor,
               int2* __restrict__ pr, int nnz) {
  int i = blockIdx.x * 256 + threadIdx.x;
  if (i < nnz) {
    int r = rows[i];
    int p = atomicAdd(&cursor[r], 1);
    pr[p] = make_int2(cols[i], __float_as_int(vals[i]));
  }
}

// ----------------------------- CSR SpMM ------------------------------------
// One wave (64 lanes) per output row; each lane owns 2 features (float2).
__device__ __forceinline__ float2 sig2(float2 a) {
  a.x = 1.f / (1.f + __expf(-a.x));
  a.y = 1.f / (1.f + __expf(-a.y));
  return a;
}

template <bool SIG>
__global__ __launch_bounds__(256)
void csr_spmm(const int* __restrict__ ptr, const int2* __restrict__ pr,
              const float* __restrict__ X, float* __restrict__ Y, int n_rows) {
  const int wid = (blockIdx.x << 2) + (threadIdx.x >> 6);
  if (wid >= n_rows) return;
  const int lane = threadIdx.x & 63;
  const float2* X2 = (const float2*)X;
  int j = ptr[wid];
  const int je = ptr[wid + 1];
  float2 acc = make_float2(0.f, 0.f);
  for (; j + 4 <= je; j += 4) {
    int2 p0 = pr[j], p1 = pr[j + 1], p2 = pr[j + 2], p3 = pr[j + 3];
    float2 a0 = X2[(size_t)p0.x * 64 + lane];
    float2 a1 = X2[(size_t)p1.x * 64 + lane];
    float2 a2 = X2[(size_t)p2.x * 64 + lane];
    float2 a3 = X2[(size_t)p3.x * 64 + lane];
    float v0 = __int_as_float(p0.y), v1 = __int_as_float(p1.y);
    float v2 = __int_as_float(p2.y), v3 = __int_as_float(p3.y);
    acc.x += v0 * a0.x + v1 * a1.x + v2 * a2.x + v3 * a3.x;
    acc.y += v0 * a0.y + v1 * a1.y + v2 * a2.y + v3 * a3.y;
  }
  for (; j < je; ++j) {
    int2 p = pr[j];
    float2 a = X2[(size_t)p.x * 64 + lane];
    float v = __int_as_float(p.y);
    acc.x += v * a.x;
    acc.y += v * a.y;
  }
  if (SIG) acc = sig2(acc);
  ((float2*)Y)[(size_t)wid * 64 + lane] = acc;
}

// Fused level-2 merge: out[r] = sigmoid( adj-seg(XA) + inc-seg(XB) )
__global__ __launch_bounds__(256)
void csr_spmm2_sig(const int* __restrict__ ptrA, const int2* __restrict__ prA,
                   const float* __restrict__ XA,
                   const int* __restrict__ ptrB, const int2* __restrict__ prB,
                   const float* __restrict__ XB,
                   float* __restrict__ Y, int n_rows) {
  const int wid = (blockIdx.x << 2) + (threadIdx.x >> 6);
  if (wid >= n_rows) return;
  const int lane = threadIdx.x & 63;
  float2 acc = make_float2(0.f, 0.f);
  {
    const float2* X2 = (const float2*)XA;
    int j = ptrA[wid];
    const int je = ptrA[wid + 1];
    for (; j + 4 <= je; j += 4) {
      int2 p0 = prA[j], p1 = prA[j + 1], p2 = prA[j + 2], p3 = prA[j + 3];
      float2 a0 = X2[(size_t)p0.x * 64 + lane];
      float2 a1 = X2[(size_t)p1.x * 64 + lane];
      float2 a2 = X2[(size_t)p2.x * 64 + lane];
      float2 a3 = X2[(size_t)p3.x * 64 + lane];
      float v0 = __int_as_float(p0.y), v1 = __int_as_float(p1.y);
      float v2 = __int_as_float(p2.y), v3 = __int_as_float(p3.y);
      acc.x += v0 * a0.x + v1 * a1.x + v2 * a2.x + v3 * a3.x;
      acc.y += v0 * a0.y + v1 * a1.y + v2 * a2.y + v3 * a3.y;
    }
    for (; j < je; ++j) {
      int2 p = prA[j];
      float2 a = X2[(size_t)p.x * 64 + lane];
      float v = __int_as_float(p.y);
      acc.x += v * a.x;
      acc.y += v * a.y;
    }
  }
  {
    const float2* X2 = (const float2*)XB;
    int j = ptrB[wid];
    const int je = ptrB[wid + 1];
    for (; j + 2 <= je; j += 2) {
      int2 p0 = prB[j], p1 = prB[j + 1];
      float2 a0 = X2[(size_t)p0.x * 64 + lane];
      float2 a1 = X2[(size_t)p1.x * 64 + lane];
      float v0 = __int_as_float(p0.y), v1 = __int_as_float(p1.y);
      acc.x += v0 * a0.x + v1 * a1.x;
      acc.y += v0 * a0.y + v1 * a1.y;
    }
    for (; j < je; ++j) {
      int2 p = prB[j];
      float2 a = X2[(size_t)p.x * 64 + lane];
      float v = __int_as_float(p.y);
      acc.x += v * a.x;
      acc.y += v * a.y;
    }
  }
  acc = sig2(acc);
  ((float2*)Y)[(size_t)wid * 64 + lane] = acc;
}

// ---------------------------------------------------------------------------
extern "C" void kernel_launch(void* const* d_in, const int* in_sizes, int n_in,
                              void* d_out, int out_size, void* d_ws, size_t ws_size,
                              hipStream_t stream) {
  const float* x      = (const float*)d_in[0];
  const float* W1_00  = (const float*)d_in[1];
  const float* W1_01  = (const float*)d_in[2];
  const float* W2_00  = (const float*)d_in[3];
  const float* W2_10  = (const float*)d_in[4];
  const int*   adj_rows = (const int*)d_in[5];
  const int*   adj_cols = (const int*)d_in[6];
  const float* adj_vals = (const float*)d_in[7];
  const int*   inc_rows = (const int*)d_in[8];
  const int*   inc_cols = (const int*)d_in[9];
  const float* inc_vals = (const float*)d_in[10];

  const int adj_nnz = in_sizes[5];       // 3,200,000
  const int inc_nnz = in_sizes[8];       // 400,000
  const int NN = in_sizes[0] / CF;       // 100,000 nodes
  const int EN = 200000;                 // edges (problem constant)

  const long long NE = (long long)NN * CF;   // 12.8M floats
  const long long EE = (long long)EN * CF;   // 25.6M floats

  // ---- workspace layout (floats/ints are 4B units) ----
  float* wsf = (float*)d_ws;
  float* tA = wsf;               // NE : t2 = x@W1_01
  float* n1 = tA + NE;           // NE : sig(adj spmm), then in-place t3
  float* e1 = n1 + NE;           // EE : sig(incT spmm), then in-place t4
  int*   ptr_a = (int*)(e1 + EE);          // NN+1
  int*   cur_a = ptr_a + (NN + 1);         // NN+1 (counts, then cursors)
  int2*  pr_a  = (int2*)(cur_a + (NN + 1));    // adj_nnz pairs
  int*   ptr_e = (int*)(pr_a + adj_nnz);   // EN+1
  int*   cur_e = ptr_e + (EN + 1);
  int2*  pr_e  = (int2*)(cur_e + (EN + 1));    // inc_nnz pairs (by edge)
  int*   ptr_i = (int*)(pr_e + inc_nnz);   // NN+1
  int*   cur_i = ptr_i + (NN + 1);
  int2*  pr_i  = (int2*)(cur_i + (NN + 1));    // inc_nnz pairs (by node)
  int*   blks  = (int*)(pr_i + inc_nnz);   // 1024 scratch

  float* t1 = (float*)d_out;     // x@W1_00 lives in d_out until the final write
  float* outf = (float*)d_out;

  const dim3 blk(256);
  const int gN  = (NN + 127) / 128;        // gemm blocks, node-rows
  const int gE  = (EN + 127) / 128;        // gemm blocks, edge-rows
  const int nbN = (NN + 1 + 1023) / 1024;  // scan blocks
  const int nbE = (EN + 1 + 1023) / 1024;

  // ---- build CSR: adj by adj_rows ----
  hipMemsetAsync(cur_a, 0, (NN + 1) * sizeof(int), stream);
  hist_k<<<(adj_nnz + 255) / 256, blk, 0, stream>>>(adj_rows, cur_a, adj_nnz);
  scan_block<<<nbN, blk, 0, stream>>>(cur_a, ptr_a, blks, NN + 1);
  scan_sums<<<1, 64, 0, stream>>>(blks, nbN);
  scan_add<<<nbN, blk, 0, stream>>>(ptr_a, cur_a, blks, NN + 1);
  scatter_k<<<(adj_nnz + 255) / 256, blk, 0, stream>>>(adj_rows, adj_cols, adj_vals, cur_a, pr_a, adj_nnz);

  // ---- build CSR: incT by inc_cols (rows = edges, cols = nodes) ----
  hipMemsetAsync(cur_e, 0, (EN + 1) * sizeof(int), stream);
  hist_k<<<(inc_nnz + 255) / 256, blk, 0, stream>>>(inc_cols, cur_e, inc_nnz);
  scan_block<<<nbE, blk, 0, stream>>>(cur_e, ptr_e, blks, EN + 1);
  scan_sums<<<1, 64, 0, stream>>>(blks, nbE);
  scan_add<<<nbE, blk, 0, stream>>>(ptr_e, cur_e, blks, EN + 1);
  scatter_k<<<(inc_nnz + 255) / 256, blk, 0, stream>>>(inc_cols, inc_rows, inc_vals, cur_e, pr_e, inc_nnz);

  // ---- build CSR: inc by inc_rows (rows = nodes, cols = edges) ----
  hipMemsetAsync(cur_i, 0, (NN + 1) * sizeof(int), stream);
  hist_k<<<(inc_nnz + 255) / 256, blk, 0, stream>>>(inc_rows, cur_i, inc_nnz);
  scan_block<<<nbN, blk, 0, stream>>>(cur_i, ptr_i, blks, NN + 1);
  scan_sums<<<1, 64, 0, stream>>>(blks, nbN);
  scan_add<<<nbN, blk, 0, stream>>>(ptr_i, cur_i, blks, NN + 1);
  scatter_k<<<(inc_nnz + 255) / 256, blk, 0, stream>>>(inc_rows, inc_cols, inc_vals, cur_i, pr_i, inc_nnz);

  // ---- level 1 GEMMs ----
  gemm128<<<gN, blk, 0, stream>>>(x, W1_00, t1, NN);
  gemm128<<<gN, blk, 0, stream>>>(x, W1_01, tA, NN);

  // ---- level 1 SpMMs (fused sigmoid) ----
  csr_spmm<true><<<(NN + 3) / 4, blk, 0, stream>>>(ptr_a, pr_a, t1, n1, NN);
  csr_spmm<true><<<(EN + 3) / 4, blk, 0, stream>>>(ptr_e, pr_e, tA, e1, EN);

  // ---- level 2 GEMMs (in-place) ----
  gemm128<<<gN, blk, 0, stream>>>(n1, W2_00, n1, NN);   // n1 -> t3
  gemm128<<<gE, blk, 0, stream>>>(e1, W2_10, e1, EN);   // e1 -> t4

  // ---- fused level-2 SpMMs + merge sigmoid ----
  csr_spmm2_sig<<<(NN + 3) / 4, blk, 0, stream>>>(ptr_a, pr_a, n1,
                                                  ptr_i, pr_i, e1, outf, NN);
}

// Round 3
// 1254.871 us; speedup vs baseline: 10.3073x; 1.4459x over previous
//
#include <hip/hip_runtime.h>

// HSN layer: out = sigmoid( A0 @ (sig(A0 @ (x W1_00)) W2_00) + B1 @ (sig(B1^T @ (x W1_01)) W2_10) )
// C = 128 fixed. CSR-gather SpMM (no f32 atomics) + MFMA GEMM via bf16 hi/lo
// 3-term split (near-f32 precision on matrix cores).

#define CF 128

typedef __attribute__((ext_vector_type(8))) short bf16x8;
typedef __attribute__((ext_vector_type(4))) float f32x4;

// split f32 -> bf16 hi + bf16 lo (truncation; lo captures residual, ~2^-16 rel)
__device__ __forceinline__ void splitf(float f, short& h, short& l) {
  unsigned u = __float_as_uint(f);
  h = (short)(u >> 16);
  float fh = __uint_as_float(u & 0xFFFF0000u);
  float r = f - fh;
  l = (short)(__float_as_uint(r) >> 16);
}

// ---------------------------------------------------------------------------
// Pack W[128][128] f32 (row-major [k][n]) into mfma_f32_16x16x32_bf16
// B-fragment order: frag[(s*8+t)*64+lane][j] = W[s*32+(lane>>4)*8+j][t*16+(lane&15)]
// (B-operand layout: lane holds B[k=quad*8+j][n=lane&15] — dual of the
//  m120-verified A layout.)
// ---------------------------------------------------------------------------
__global__ __launch_bounds__(256)
void pack_w(const float* __restrict__ W, short* __restrict__ hi,
            short* __restrict__ lo) {
  const int tid = blockIdx.x * 256 + threadIdx.x;   // 0..2047
  if (tid >= 2048) return;
  const int lane = tid & 63;
  const int t = (tid >> 6) & 7;
  const int s = tid >> 9;
  const int n = t * 16 + (lane & 15);
  const int k0 = s * 32 + ((lane >> 4) << 3);
  short* hp = hi + (size_t)tid * 8;
  short* lp = lo + (size_t)tid * 8;
#pragma unroll
  for (int j = 0; j < 8; ++j) {
    short h, l;
    splitf(W[(size_t)(k0 + j) * CF + n], h, l);
    hp[j] = h;
    lp[j] = l;
  }
}

// ---------------------------------------------------------------------------
// GEMM: Y[M x 128] = X[M x 128] @ W[128 x 128] via 16x16x32 bf16 MFMA,
// 3-term hi/lo split. Block = 128 threads = 2 waves; each wave owns 32 rows
// x 128 cols (2 m-tiles x 8 n-tiles, f32x4 acc each). No LDS.
// NOTE: X and Y may alias (in-place): each wave reads only the rows it
// writes, and all loads precede stores in program order — safe.
// ---------------------------------------------------------------------------
__global__ __launch_bounds__(128)
void gemm_mfma(const float* X, const short* __restrict__ Whi,
               const short* __restrict__ Wlo, float* Y, int M) {
  const int wave = threadIdx.x >> 6;
  const int lane = threadIdx.x & 63;
  const int mrow = lane & 15;
  const int quad = lane >> 4;
  const int row0 = blockIdx.x * 64 + wave * 32;

  const bf16x8* WH = (const bf16x8*)Whi;
  const bf16x8* WL = (const bf16x8*)Wlo;

  f32x4 acc[2][8];
#pragma unroll
  for (int mt = 0; mt < 2; ++mt)
#pragma unroll
    for (int t = 0; t < 8; ++t) acc[mt][t] = (f32x4){0.f, 0.f, 0.f, 0.f};

  int rA0 = row0 + mrow;      if (rA0 > M - 1) rA0 = M - 1;
  int rA1 = row0 + 16 + mrow; if (rA1 > M - 1) rA1 = M - 1;
  const float* xp0 = X + (size_t)rA0 * CF + quad * 8;
  const float* xp1 = X + (size_t)rA1 * CF + quad * 8;

#pragma unroll
  for (int s = 0; s < 4; ++s) {
    bf16x8 Ah[2], Al[2];
    {
      const float* p = xp0 + s * 32;
#pragma unroll
      for (int j = 0; j < 8; ++j) { short h, l; splitf(p[j], h, l); Ah[0][j] = h; Al[0][j] = l; }
      p = xp1 + s * 32;
#pragma unroll
      for (int j = 0; j < 8; ++j) { short h, l; splitf(p[j], h, l); Ah[1][j] = h; Al[1][j] = l; }
    }
#pragma unroll
    for (int t = 0; t < 8; ++t) {
      const bf16x8 bh = WH[(s * 8 + t) * 64 + lane];
      const bf16x8 bl = WL[(s * 8 + t) * 64 + lane];
#pragma unroll
      for (int mt = 0; mt < 2; ++mt) {
        acc[mt][t] = __builtin_amdgcn_mfma_f32_16x16x32_bf16(Ah[mt], bh, acc[mt][t], 0, 0, 0);
        acc[mt][t] = __builtin_amdgcn_mfma_f32_16x16x32_bf16(Al[mt], bh, acc[mt][t], 0, 0, 0);
        acc[mt][t] = __builtin_amdgcn_mfma_f32_16x16x32_bf16(Ah[mt], bl, acc[mt][t], 0, 0, 0);
      }
    }
  }

  // C/D layout: col = t*16 + mrow, row = row0 + mt*16 + quad*4 + reg
#pragma unroll
  for (int mt = 0; mt < 2; ++mt)
#pragma unroll
    for (int reg = 0; reg < 4; ++reg) {
      const int r = row0 + mt * 16 + quad * 4 + reg;
      if (r < M) {
        float* yp = Y + (size_t)r * CF + mrow;
#pragma unroll
        for (int t = 0; t < 8; ++t) yp[t * 16] = acc[mt][t][reg];
      }
    }
}

// --------------------------- CSR build kernels -----------------------------
__global__ __launch_bounds__(256)
void hist_k(const int* __restrict__ rows, int* __restrict__ cnt, int nnz) {
  int i = blockIdx.x * 256 + threadIdx.x;
  if (i < nnz) atomicAdd(&cnt[rows[i]], 1);
}

__global__ __launch_bounds__(256)
void scan_block(const int* __restrict__ cnt, int* __restrict__ ptr,
                int* __restrict__ blksum, int n) {
  __shared__ int sdata[256];
  const int t = threadIdx.x;
  const int idx = blockIdx.x * 1024 + t * 4;
  int v[4];
#pragma unroll
  for (int k = 0; k < 4; ++k) v[k] = (idx + k < n) ? cnt[idx + k] : 0;
  int tsum = v[0] + v[1] + v[2] + v[3];
  sdata[t] = tsum;
  __syncthreads();
  for (int off = 1; off < 256; off <<= 1) {
    int x = (t >= off) ? sdata[t - off] : 0;
    __syncthreads();
    sdata[t] += x;
    __syncthreads();
  }
  if (t == 255) blksum[blockIdx.x] = sdata[255];
  int run = sdata[t] - tsum;
#pragma unroll
  for (int k = 0; k < 4; ++k) {
    if (idx + k < n) ptr[idx + k] = run;
    run += v[k];
  }
}

__global__ void scan_sums(int* blksum, int nb) {
  if (threadIdx.x == 0) {
    int run = 0;
    for (int i = 0; i < nb; ++i) { int c = blksum[i]; blksum[i] = run; run += c; }
  }
}

__global__ __launch_bounds__(256)
void scan_add(int* __restrict__ ptr, int* __restrict__ cursor,
              const int* __restrict__ blkoff, int n) {
  const int off = blkoff[blockIdx.x];
  const int base = blockIdx.x * 1024 + threadIdx.x;
#pragma unroll
  for (int k = 0; k < 4; ++k) {
    int i = base + k * 256;
    if (i < n) { int v = ptr[i] + off; ptr[i] = v; cursor[i] = v; }
  }
}

__global__ __launch_bounds__(256)
void scatter_k(const int* __restrict__ rows, const int* __restrict__ cols,
               const float* __restrict__ vals, int* __restrict__ cursor,
               int2* __restrict__ pr, int nnz) {
  int i = blockIdx.x * 256 + threadIdx.x;
  if (i < nnz) {
    int r = rows[i];
    int p = atomicAdd(&cursor[r], 1);
    pr[p] = make_int2(cols[i], __float_as_int(vals[i]));
  }
}

// ----------------------------- CSR SpMM ------------------------------------
__device__ __forceinline__ float2 sig2(float2 a) {
  a.x = 1.f / (1.f + __expf(-a.x));
  a.y = 1.f / (1.f + __expf(-a.y));
  return a;
}

template <bool SIG>
__global__ __launch_bounds__(256)
void csr_spmm(const int* __restrict__ ptr, const int2* __restrict__ pr,
              const float* __restrict__ X, float* __restrict__ Y, int n_rows) {
  const int wid = (blockIdx.x << 2) + (threadIdx.x >> 6);
  if (wid >= n_rows) return;
  const int lane = threadIdx.x & 63;
  const float2* X2 = (const float2*)X;
  int j = ptr[wid];
  const int je = ptr[wid + 1];
  float2 acc = make_float2(0.f, 0.f);
  for (; j + 4 <= je; j += 4) {
    int2 p0 = pr[j], p1 = pr[j + 1], p2 = pr[j + 2], p3 = pr[j + 3];
    float2 a0 = X2[(size_t)p0.x * 64 + lane];
    float2 a1 = X2[(size_t)p1.x * 64 + lane];
    float2 a2 = X2[(size_t)p2.x * 64 + lane];
    float2 a3 = X2[(size_t)p3.x * 64 + lane];
    float v0 = __int_as_float(p0.y), v1 = __int_as_float(p1.y);
    float v2 = __int_as_float(p2.y), v3 = __int_as_float(p3.y);
    acc.x += v0 * a0.x + v1 * a1.x + v2 * a2.x + v3 * a3.x;
    acc.y += v0 * a0.y + v1 * a1.y + v2 * a2.y + v3 * a3.y;
  }
  for (; j < je; ++j) {
    int2 p = pr[j];
    float2 a = X2[(size_t)p.x * 64 + lane];
    float v = __int_as_float(p.y);
    acc.x += v * a.x;
    acc.y += v * a.y;
  }
  if (SIG) acc = sig2(acc);
  ((float2*)Y)[(size_t)wid * 64 + lane] = acc;
}

__global__ __launch_bounds__(256)
void csr_spmm2_sig(const int* __restrict__ ptrA, const int2* __restrict__ prA,
                   const float* __restrict__ XA,
                   const int* __restrict__ ptrB, const int2* __restrict__ prB,
                   const float* __restrict__ XB,
                   float* __restrict__ Y, int n_rows) {
  const int wid = (blockIdx.x << 2) + (threadIdx.x >> 6);
  if (wid >= n_rows) return;
  const int lane = threadIdx.x & 63;
  float2 acc = make_float2(0.f, 0.f);
  {
    const float2* X2 = (const float2*)XA;
    int j = ptrA[wid];
    const int je = ptrA[wid + 1];
    for (; j + 4 <= je; j += 4) {
      int2 p0 = prA[j], p1 = prA[j + 1], p2 = prA[j + 2], p3 = prA[j + 3];
      float2 a0 = X2[(size_t)p0.x * 64 + lane];
      float2 a1 = X2[(size_t)p1.x * 64 + lane];
      float2 a2 = X2[(size_t)p2.x * 64 + lane];
      float2 a3 = X2[(size_t)p3.x * 64 + lane];
      float v0 = __int_as_float(p0.y), v1 = __int_as_float(p1.y);
      float v2 = __int_as_float(p2.y), v3 = __int_as_float(p3.y);
      acc.x += v0 * a0.x + v1 * a1.x + v2 * a2.x + v3 * a3.x;
      acc.y += v0 * a0.y + v1 * a1.y + v2 * a2.y + v3 * a3.y;
    }
    for (; j < je; ++j) {
      int2 p = prA[j];
      float2 a = X2[(size_t)p.x * 64 + lane];
      float v = __int_as_float(p.y);
      acc.x += v * a.x;
      acc.y += v * a.y;
    }
  }
  {
    const float2* X2 = (const float2*)XB;
    int j = ptrB[wid];
    const int je = ptrB[wid + 1];
    for (; j + 2 <= je; j += 2) {
      int2 p0 = prB[j], p1 = prB[j + 1];
      float2 a0 = X2[(size_t)p0.x * 64 + lane];
      float2 a1 = X2[(size_t)p1.x * 64 + lane];
      float v0 = __int_as_float(p0.y), v1 = __int_as_float(p1.y);
      acc.x += v0 * a0.x + v1 * a1.x;
      acc.y += v0 * a0.y + v1 * a1.y;
    }
    for (; j < je; ++j) {
      int2 p = prB[j];
      float2 a = X2[(size_t)p.x * 64 + lane];
      float v = __int_as_float(p.y);
      acc.x += v * a.x;
      acc.y += v * a.y;
    }
  }
  acc = sig2(acc);
  ((float2*)Y)[(size_t)wid * 64 + lane] = acc;
}

// ---------------------------------------------------------------------------
extern "C" void kernel_launch(void* const* d_in, const int* in_sizes, int n_in,
                              void* d_out, int out_size, void* d_ws, size_t ws_size,
                              hipStream_t stream) {
  const float* x      = (const float*)d_in[0];
  const float* W1_00  = (const float*)d_in[1];
  const float* W1_01  = (const float*)d_in[2];
  const float* W2_00  = (const float*)d_in[3];
  const float* W2_10  = (const float*)d_in[4];
  const int*   adj_rows = (const int*)d_in[5];
  const int*   adj_cols = (const int*)d_in[6];
  const float* adj_vals = (const float*)d_in[7];
  const int*   inc_rows = (const int*)d_in[8];
  const int*   inc_cols = (const int*)d_in[9];
  const float* inc_vals = (const float*)d_in[10];

  const int adj_nnz = in_sizes[5];       // 3,200,000
  const int inc_nnz = in_sizes[8];       // 400,000
  const int NN = in_sizes[0] / CF;       // 100,000 nodes
  const int EN = 200000;                 // edges (problem constant)

  const long long NE = (long long)NN * CF;
  const long long EE = (long long)EN * CF;

  // ---- workspace layout ----
  float* wsf = (float*)d_ws;
  float* tA = wsf;               // NE : t2 = x@W1_01
  float* n1 = tA + NE;           // NE : sig(adj spmm) -> in-place t3
  float* e1 = n1 + NE;           // EE : sig(incT spmm) -> in-place t4
  int*   ptr_a = (int*)(e1 + EE);
  int*   cur_a = ptr_a + (NN + 1);
  int2*  pr_a  = (int2*)(cur_a + (NN + 1));
  int*   ptr_e = (int*)(pr_a + adj_nnz);
  int*   cur_e = ptr_e + (EN + 1);
  int2*  pr_e  = (int2*)(cur_e + (EN + 1));
  int*   ptr_i = (int*)(pr_e + inc_nnz);
  int*   cur_i = ptr_i + (NN + 1);
  int2*  pr_i  = (int2*)(cur_i + (NN + 1));
  int*   blks  = (int*)(pr_i + inc_nnz);   // 1024 ints
  // packed W fragments (16B-aligned)
  short* wp = (short*)(((uintptr_t)(blks + 1024) + 63) & ~(uintptr_t)63);
  short* w00h = wp;            short* w00l = wp + 16384;
  short* w01h = wp + 2*16384;  short* w01l = wp + 3*16384;
  short* w20h = wp + 4*16384;  short* w20l = wp + 5*16384;
  short* w21h = wp + 6*16384;  short* w21l = wp + 7*16384;

  float* t1 = (float*)d_out;
  float* outf = (float*)d_out;

  const dim3 blk(256);
  const int nbN = (NN + 1 + 1023) / 1024;
  const int nbE = (EN + 1 + 1023) / 1024;
  const int gN = (NN + 63) / 64;   // gemm blocks (64 rows each)
  const int gE = (EN + 63) / 64;

  // ---- pack weights into MFMA B-fragment hi/lo ----
  pack_w<<<8, blk, 0, stream>>>(W1_00, w00h, w00l);
  pack_w<<<8, blk, 0, stream>>>(W1_01, w01h, w01l);
  pack_w<<<8, blk, 0, stream>>>(W2_00, w20h, w20l);
  pack_w<<<8, blk, 0, stream>>>(W2_10, w21h, w21l);

  // ---- build CSR: adj by adj_rows ----
  hipMemsetAsync(cur_a, 0, (NN + 1) * sizeof(int), stream);
  hist_k<<<(adj_nnz + 255) / 256, blk, 0, stream>>>(adj_rows, cur_a, adj_nnz);
  scan_block<<<nbN, blk, 0, stream>>>(cur_a, ptr_a, blks, NN + 1);
  scan_sums<<<1, 64, 0, stream>>>(blks, nbN);
  scan_add<<<nbN, blk, 0, stream>>>(ptr_a, cur_a, blks, NN + 1);
  scatter_k<<<(adj_nnz + 255) / 256, blk, 0, stream>>>(adj_rows, adj_cols, adj_vals, cur_a, pr_a, adj_nnz);

  // ---- build CSR: incT by inc_cols ----
  hipMemsetAsync(cur_e, 0, (EN + 1) * sizeof(int), stream);
  hist_k<<<(inc_nnz + 255) / 256, blk, 0, stream>>>(inc_cols, cur_e, inc_nnz);
  scan_block<<<nbE, blk, 0, stream>>>(cur_e, ptr_e, blks, EN + 1);
  scan_sums<<<1, 64, 0, stream>>>(blks, nbE);
  scan_add<<<nbE, blk, 0, stream>>>(ptr_e, cur_e, blks, EN + 1);
  scatter_k<<<(inc_nnz + 255) / 256, blk, 0, stream>>>(inc_cols, inc_rows, inc_vals, cur_e, pr_e, inc_nnz);

  // ---- build CSR: inc by inc_rows ----
  hipMemsetAsync(cur_i, 0, (NN + 1) * sizeof(int), stream);
  hist_k<<<(inc_nnz + 255) / 256, blk, 0, stream>>>(inc_rows, cur_i, inc_nnz);
  scan_block<<<nbN, blk, 0, stream>>>(cur_i, ptr_i, blks, NN + 1);
  scan_sums<<<1, 64, 0, stream>>>(blks, nbN);
  scan_add<<<nbN, blk, 0, stream>>>(ptr_i, cur_i, blks, NN + 1);
  scatter_k<<<(inc_nnz + 255) / 256, blk, 0, stream>>>(inc_rows, inc_cols, inc_vals, cur_i, pr_i, inc_nnz);

  // ---- level 1 GEMMs ----
  gemm_mfma<<<gN, dim3(128), 0, stream>>>(x, w00h, w00l, t1, NN);
  gemm_mfma<<<gN, dim3(128), 0, stream>>>(x, w01h, w01l, tA, NN);

  // ---- level 1 SpMMs (fused sigmoid) ----
  csr_spmm<true><<<(NN + 3) / 4, blk, 0, stream>>>(ptr_a, pr_a, t1, n1, NN);
  csr_spmm<true><<<(EN + 3) / 4, blk, 0, stream>>>(ptr_e, pr_e, tA, e1, EN);

  // ---- level 2 GEMMs (in-place) ----
  gemm_mfma<<<gN, dim3(128), 0, stream>>>(n1, w20h, w20l, n1, NN);
  gemm_mfma<<<gE, dim3(128), 0, stream>>>(e1, w21h, w21l, e1, EN);

  // ---- fused level-2 SpMMs + merge sigmoid ----
  csr_spmm2_sig<<<(NN + 3) / 4, blk, 0, stream>>>(ptr_a, pr_a, n1,
                                                  ptr_i, pr_i, e1, outf, NN);
}

// Round 4
// 996.645 us; speedup vs baseline: 12.9779x; 1.2591x over previous
//
#include <hip/hip_runtime.h>

// HSN layer: out = sigmoid( A0 @ (sig(A0 @ (x W1_00)) W2_00) + B1 @ (sig(B1^T @ (x W1_01)) W2_10) )
// C = 128 fixed. CSR-gather SpMM (no f32 atomics) + MFMA GEMMs.
// All intermediate feature matrices stored as bf16 (256 B/row) to halve the
// L2-miss gather traffic that bounds the SpMM kernels.

#define CF 128

typedef __attribute__((ext_vector_type(8))) short bf16x8;
typedef __attribute__((ext_vector_type(4))) float f32x4;

// f32 -> bf16 round-to-nearest-even (finite inputs)
__device__ __forceinline__ unsigned short bf16rne(float f) {
  unsigned u = __float_as_uint(f);
  u += 0x7FFFu + ((u >> 16) & 1u);
  return (unsigned short)(u >> 16);
}
// packed pair of bf16 (low short = even feature) -> two floats
__device__ __forceinline__ float2 bf2f(unsigned u) {
  return make_float2(__uint_as_float(u << 16), __uint_as_float(u & 0xFFFF0000u));
}
// split f32 -> bf16 hi (trunc) + bf16 lo (residual)
__device__ __forceinline__ void splitf(float f, short& h, short& l) {
  unsigned u = __float_as_uint(f);
  h = (short)(u >> 16);
  float fh = __uint_as_float(u & 0xFFFF0000u);
  float r = f - fh;
  l = (short)(__float_as_uint(r) >> 16);
}

// ---------------------------------------------------------------------------
// Pack W[128][128] f32 (row-major [k][n]) into mfma_f32_16x16x32_bf16
// B-fragment order: frag[(s*8+t)*64+lane][j] = W[s*32+(lane>>4)*8+j][t*16+(lane&15)]
// ---------------------------------------------------------------------------
__global__ __launch_bounds__(256)
void pack_w(const float* __restrict__ W, short* __restrict__ hi,
            short* __restrict__ lo) {
  const int tid = blockIdx.x * 256 + threadIdx.x;   // 0..2047
  if (tid >= 2048) return;
  const int lane = tid & 63;
  const int t = (tid >> 6) & 7;
  const int s = tid >> 9;
  const int n = t * 16 + (lane & 15);
  const int k0 = s * 32 + ((lane >> 4) << 3);
  short* hp = hi + (size_t)tid * 8;
  short* lp = lo + (size_t)tid * 8;
#pragma unroll
  for (int j = 0; j < 8; ++j) {
    short h, l;
    splitf(W[(size_t)(k0 + j) * CF + n], h, l);
    hp[j] = h;
    lp[j] = l;
  }
}

// ---------------------------------------------------------------------------
// GEMM (f32 in, bf16 out): Y = X @ W, 3-term hi/lo split MFMA.
// Block = 128 thr = 2 waves; each wave owns 32 rows x 128 cols.
// ---------------------------------------------------------------------------
__global__ __launch_bounds__(128)
void gemm_f32_b16(const float* __restrict__ X, const short* __restrict__ Whi,
                  const short* __restrict__ Wlo, unsigned short* __restrict__ Y,
                  int M) {
  const int wave = threadIdx.x >> 6;
  const int lane = threadIdx.x & 63;
  const int mrow = lane & 15;
  const int quad = lane >> 4;
  const int row0 = blockIdx.x * 64 + wave * 32;

  const bf16x8* WH = (const bf16x8*)Whi;
  const bf16x8* WL = (const bf16x8*)Wlo;

  f32x4 acc[2][8];
#pragma unroll
  for (int mt = 0; mt < 2; ++mt)
#pragma unroll
    for (int t = 0; t < 8; ++t) acc[mt][t] = (f32x4){0.f, 0.f, 0.f, 0.f};

  int rA0 = row0 + mrow;      if (rA0 > M - 1) rA0 = M - 1;
  int rA1 = row0 + 16 + mrow; if (rA1 > M - 1) rA1 = M - 1;
  const float* xp0 = X + (size_t)rA0 * CF + quad * 8;
  const float* xp1 = X + (size_t)rA1 * CF + quad * 8;

#pragma unroll
  for (int s = 0; s < 4; ++s) {
    bf16x8 Ah[2], Al[2];
    const float* p = xp0 + s * 32;
#pragma unroll
    for (int j = 0; j < 8; ++j) { short h, l; splitf(p[j], h, l); Ah[0][j] = h; Al[0][j] = l; }
    p = xp1 + s * 32;
#pragma unroll
    for (int j = 0; j < 8; ++j) { short h, l; splitf(p[j], h, l); Ah[1][j] = h; Al[1][j] = l; }
#pragma unroll
    for (int t = 0; t < 8; ++t) {
      const bf16x8 bh = WH[(s * 8 + t) * 64 + lane];
      const bf16x8 bl = WL[(s * 8 + t) * 64 + lane];
#pragma unroll
      for (int mt = 0; mt < 2; ++mt) {
        acc[mt][t] = __builtin_amdgcn_mfma_f32_16x16x32_bf16(Ah[mt], bh, acc[mt][t], 0, 0, 0);
        acc[mt][t] = __builtin_amdgcn_mfma_f32_16x16x32_bf16(Al[mt], bh, acc[mt][t], 0, 0, 0);
        acc[mt][t] = __builtin_amdgcn_mfma_f32_16x16x32_bf16(Ah[mt], bl, acc[mt][t], 0, 0, 0);
      }
    }
  }

#pragma unroll
  for (int mt = 0; mt < 2; ++mt)
#pragma unroll
    for (int reg = 0; reg < 4; ++reg) {
      const int r = row0 + mt * 16 + quad * 4 + reg;
      if (r < M) {
        unsigned short* yp = Y + (size_t)r * CF + mrow;
#pragma unroll
        for (int t = 0; t < 8; ++t) yp[t * 16] = bf16rne(acc[mt][t][reg]);
      }
    }
}

// ---------------------------------------------------------------------------
// GEMM (bf16 in, bf16 out): Y = X @ W, 2-term (W split) MFMA. In-place safe:
// each wave reads only rows it writes; OOB waves' results are discarded.
// ---------------------------------------------------------------------------
__global__ __launch_bounds__(128)
void gemm_b16_b16(const unsigned short* __restrict__ X,
                  const short* __restrict__ Whi, const short* __restrict__ Wlo,
                  unsigned short* __restrict__ Y, int M) {
  const int wave = threadIdx.x >> 6;
  const int lane = threadIdx.x & 63;
  const int mrow = lane & 15;
  const int quad = lane >> 4;
  const int row0 = blockIdx.x * 64 + wave * 32;

  const bf16x8* WH = (const bf16x8*)Whi;
  const bf16x8* WL = (const bf16x8*)Wlo;

  f32x4 acc[2][8];
#pragma unroll
  for (int mt = 0; mt < 2; ++mt)
#pragma unroll
    for (int t = 0; t < 8; ++t) acc[mt][t] = (f32x4){0.f, 0.f, 0.f, 0.f};

  int rA0 = row0 + mrow;      if (rA0 > M - 1) rA0 = M - 1;
  int rA1 = row0 + 16 + mrow; if (rA1 > M - 1) rA1 = M - 1;
  const bf16x8* xp0 = (const bf16x8*)(X + (size_t)rA0 * CF + quad * 8);
  const bf16x8* xp1 = (const bf16x8*)(X + (size_t)rA1 * CF + quad * 8);

#pragma unroll
  for (int s = 0; s < 4; ++s) {
    bf16x8 A0 = xp0[s * 4];   // s*32 shorts = s*4 bf16x8
    bf16x8 A1 = xp1[s * 4];
#pragma unroll
    for (int t = 0; t < 8; ++t) {
      const bf16x8 bh = WH[(s * 8 + t) * 64 + lane];
      const bf16x8 bl = WL[(s * 8 + t) * 64 + lane];
      acc[0][t] = __builtin_amdgcn_mfma_f32_16x16x32_bf16(A0, bh, acc[0][t], 0, 0, 0);
      acc[0][t] = __builtin_amdgcn_mfma_f32_16x16x32_bf16(A0, bl, acc[0][t], 0, 0, 0);
      acc[1][t] = __builtin_amdgcn_mfma_f32_16x16x32_bf16(A1, bh, acc[1][t], 0, 0, 0);
      acc[1][t] = __builtin_amdgcn_mfma_f32_16x16x32_bf16(A1, bl, acc[1][t], 0, 0, 0);
    }
  }

#pragma unroll
  for (int mt = 0; mt < 2; ++mt)
#pragma unroll
    for (int reg = 0; reg < 4; ++reg) {
      const int r = row0 + mt * 16 + quad * 4 + reg;
      if (r < M) {
        unsigned short* yp = Y + (size_t)r * CF + mrow;
#pragma unroll
        for (int t = 0; t < 8; ++t) yp[t * 16] = bf16rne(acc[mt][t][reg]);
      }
    }
}

// --------------------------- CSR build kernels -----------------------------
__global__ __launch_bounds__(256)
void hist_k(const int* __restrict__ rows, int* __restrict__ cnt, int nnz) {
  int i = blockIdx.x * 256 + threadIdx.x;
  if (i < nnz) atomicAdd(&cnt[rows[i]], 1);
}

__global__ __launch_bounds__(256)
void scan_block(const int* __restrict__ cnt, int* __restrict__ ptr,
                int* __restrict__ blksum, int n) {
  __shared__ int sdata[256];
  const int t = threadIdx.x;
  const int idx = blockIdx.x * 1024 + t * 4;
  int v[4];
#pragma unroll
  for (int k = 0; k < 4; ++k) v[k] = (idx + k < n) ? cnt[idx + k] : 0;
  int tsum = v[0] + v[1] + v[2] + v[3];
  sdata[t] = tsum;
  __syncthreads();
  for (int off = 1; off < 256; off <<= 1) {
    int x = (t >= off) ? sdata[t - off] : 0;
    __syncthreads();
    sdata[t] += x;
    __syncthreads();
  }
  if (t == 255) blksum[blockIdx.x] = sdata[255];
  int run = sdata[t] - tsum;
#pragma unroll
  for (int k = 0; k < 4; ++k) {
    if (idx + k < n) ptr[idx + k] = run;
    run += v[k];
  }
}

__global__ void scan_sums(int* blksum, int nb) {
  if (threadIdx.x == 0) {
    int run = 0;
    for (int i = 0; i < nb; ++i) { int c = blksum[i]; blksum[i] = run; run += c; }
  }
}

__global__ __launch_bounds__(256)
void scan_add(int* __restrict__ ptr, int* __restrict__ cursor,
              const int* __restrict__ blkoff, int n) {
  const int off = blkoff[blockIdx.x];
  const int base = blockIdx.x * 1024 + threadIdx.x;
#pragma unroll
  for (int k = 0; k < 4; ++k) {
    int i = base + k * 256;
    if (i < n) { int v = ptr[i] + off; ptr[i] = v; cursor[i] = v; }
  }
}

__global__ __launch_bounds__(256)
void scatter_k(const int* __restrict__ rows, const int* __restrict__ cols,
               const float* __restrict__ vals, int* __restrict__ cursor,
               int2* __restrict__ pr, int nnz) {
  int i = blockIdx.x * 256 + threadIdx.x;
  if (i < nnz) {
    int r = rows[i];
    int p = atomicAdd(&cursor[r], 1);
    pr[p] = make_int2(cols[i], __float_as_int(vals[i]));
  }
}

// ----------------------------- CSR SpMM (bf16 features) --------------------
// One wave per output row; each lane owns 2 features (one packed uint).
template <bool SIG>
__global__ __launch_bounds__(256)
void csr_spmm_b16(const int* __restrict__ ptr, const int2* __restrict__ pr,
                  const unsigned* __restrict__ X, unsigned* __restrict__ Y,
                  int n_rows) {
  const int wid = (blockIdx.x << 2) + (threadIdx.x >> 6);
  if (wid >= n_rows) return;
  const int lane = threadIdx.x & 63;
  int j = ptr[wid];
  const int je = ptr[wid + 1];
  float2 acc = make_float2(0.f, 0.f);
  for (; j + 4 <= je; j += 4) {
    int2 p0 = pr[j], p1 = pr[j + 1], p2 = pr[j + 2], p3 = pr[j + 3];
    float2 a0 = bf2f(X[(size_t)p0.x * 64 + lane]);
    float2 a1 = bf2f(X[(size_t)p1.x * 64 + lane]);
    float2 a2 = bf2f(X[(size_t)p2.x * 64 + lane]);
    float2 a3 = bf2f(X[(size_t)p3.x * 64 + lane]);
    float v0 = __int_as_float(p0.y), v1 = __int_as_float(p1.y);
    float v2 = __int_as_float(p2.y), v3 = __int_as_float(p3.y);
    acc.x += v0 * a0.x + v1 * a1.x + v2 * a2.x + v3 * a3.x;
    acc.y += v0 * a0.y + v1 * a1.y + v2 * a2.y + v3 * a3.y;
  }
  for (; j < je; ++j) {
    int2 p = pr[j];
    float2 a = bf2f(X[(size_t)p.x * 64 + lane]);
    float v = __int_as_float(p.y);
    acc.x += v * a.x;
    acc.y += v * a.y;
  }
  if (SIG) {
    acc.x = 1.f / (1.f + __expf(-acc.x));
    acc.y = 1.f / (1.f + __expf(-acc.y));
  }
  Y[(size_t)wid * 64 + lane] =
      (unsigned)bf16rne(acc.x) | ((unsigned)bf16rne(acc.y) << 16);
}

// Fused level-2 merge: out[r] = sigmoid( adj-seg(XA) + inc-seg(XB) ), f32 out.
__global__ __launch_bounds__(256)
void csr_spmm2_sig(const int* __restrict__ ptrA, const int2* __restrict__ prA,
                   const unsigned* __restrict__ XA,
                   const int* __restrict__ ptrB, const int2* __restrict__ prB,
                   const unsigned* __restrict__ XB,
                   float* __restrict__ Y, int n_rows) {
  const int wid = (blockIdx.x << 2) + (threadIdx.x >> 6);
  if (wid >= n_rows) return;
  const int lane = threadIdx.x & 63;
  float2 acc = make_float2(0.f, 0.f);
  {
    int j = ptrA[wid];
    const int je = ptrA[wid + 1];
    for (; j + 4 <= je; j += 4) {
      int2 p0 = prA[j], p1 = prA[j + 1], p2 = prA[j + 2], p3 = prA[j + 3];
      float2 a0 = bf2f(XA[(size_t)p0.x * 64 + lane]);
      float2 a1 = bf2f(XA[(size_t)p1.x * 64 + lane]);
      float2 a2 = bf2f(XA[(size_t)p2.x * 64 + lane]);
      float2 a3 = bf2f(XA[(size_t)p3.x * 64 + lane]);
      float v0 = __int_as_float(p0.y), v1 = __int_as_float(p1.y);
      float v2 = __int_as_float(p2.y), v3 = __int_as_float(p3.y);
      acc.x += v0 * a0.x + v1 * a1.x + v2 * a2.x + v3 * a3.x;
      acc.y += v0 * a0.y + v1 * a1.y + v2 * a2.y + v3 * a3.y;
    }
    for (; j < je; ++j) {
      int2 p = prA[j];
      float2 a = bf2f(XA[(size_t)p.x * 64 + lane]);
      float v = __int_as_float(p.y);
      acc.x += v * a.x;
      acc.y += v * a.y;
    }
  }
  {
    int j = ptrB[wid];
    const int je = ptrB[wid + 1];
    for (; j + 2 <= je; j += 2) {
      int2 p0 = prB[j], p1 = prB[j + 1];
      float2 a0 = bf2f(XB[(size_t)p0.x * 64 + lane]);
      float2 a1 = bf2f(XB[(size_t)p1.x * 64 + lane]);
      float v0 = __int_as_float(p0.y), v1 = __int_as_float(p1.y);
      acc.x += v0 * a0.x + v1 * a1.x;
      acc.y += v0 * a0.y + v1 * a1.y;
    }
    for (; j < je; ++j) {
      int2 p = prB[j];
      float2 a = bf2f(XB[(size_t)p.x * 64 + lane]);
      float v = __int_as_float(p.y);
      acc.x += v * a.x;
      acc.y += v * a.y;
    }
  }
  acc.x = 1.f / (1.f + __expf(-acc.x));
  acc.y = 1.f / (1.f + __expf(-acc.y));
  ((float2*)Y)[(size_t)wid * 64 + lane] = acc;
}

// ---------------------------------------------------------------------------
extern "C" void kernel_launch(void* const* d_in, const int* in_sizes, int n_in,
                              void* d_out, int out_size, void* d_ws, size_t ws_size,
                              hipStream_t stream) {
  const float* x      = (const float*)d_in[0];
  const float* W1_00  = (const float*)d_in[1];
  const float* W1_01  = (const float*)d_in[2];
  const float* W2_00  = (const float*)d_in[3];
  const float* W2_10  = (const float*)d_in[4];
  const int*   adj_rows = (const int*)d_in[5];
  const int*   adj_cols = (const int*)d_in[6];
  const float* adj_vals = (const float*)d_in[7];
  const int*   inc_rows = (const int*)d_in[8];
  const int*   inc_cols = (const int*)d_in[9];
  const float* inc_vals = (const float*)d_in[10];

  const int adj_nnz = in_sizes[5];       // 3,200,000
  const int inc_nnz = in_sizes[8];       // 400,000
  const int NN = in_sizes[0] / CF;       // 100,000 nodes
  const int EN = 200000;                 // edges (problem constant)

  const long long NE = (long long)NN * CF;   // node features
  const long long EE = (long long)EN * CF;   // edge features
  const int PN = ((NN + 2) & ~1);            // padded (8B-align int2 arrays)
  const int PE = ((EN + 2) & ~1);

  // ---- workspace layout (bf16 features + CSR arrays + packed weights) ----
  unsigned short* tA = (unsigned short*)d_ws;   // NE bf16 : t2, then unused
  unsigned short* n1 = tA + NE;                 // NE bf16 : sig l1 -> t3
  unsigned short* e1 = n1 + NE;                 // EE bf16 : sig l1 -> t4
  int*   ptr_a = (int*)(e1 + EE);
  int*   cur_a = ptr_a + PN;
  int2*  pr_a  = (int2*)(cur_a + PN);
  int*   ptr_e = (int*)(pr_a + adj_nnz);
  int*   cur_e = ptr_e + PE;
  int2*  pr_e  = (int2*)(cur_e + PE);
  int*   ptr_i = (int*)(pr_e + inc_nnz);
  int*   cur_i = ptr_i + PN;
  int2*  pr_i  = (int2*)(cur_i + PN);
  int*   blks  = (int*)(pr_i + inc_nnz);        // 1024 ints
  short* wp = (short*)(((uintptr_t)(blks + 1024) + 63) & ~(uintptr_t)63);
  short* w00h = wp;            short* w00l = wp + 16384;
  short* w01h = wp + 2*16384;  short* w01l = wp + 3*16384;
  short* w20h = wp + 4*16384;  short* w20l = wp + 5*16384;
  short* w21h = wp + 6*16384;  short* w21l = wp + 7*16384;

  unsigned short* t1 = (unsigned short*)d_out;  // bf16 scratch; dead before final write
  float* outf = (float*)d_out;

  const dim3 blk(256);
  const int nbN = (NN + 1 + 1023) / 1024;
  const int nbE = (EN + 1 + 1023) / 1024;
  const int gN = (NN + 63) / 64;
  const int gE = (EN + 63) / 64;

  // ---- pack weights ----
  pack_w<<<8, blk, 0, stream>>>(W1_00, w00h, w00l);
  pack_w<<<8, blk, 0, stream>>>(W1_01, w01h, w01l);
  pack_w<<<8, blk, 0, stream>>>(W2_00, w20h, w20l);
  pack_w<<<8, blk, 0, stream>>>(W2_10, w21h, w21l);

  // ---- build CSR: adj by adj_rows ----
  hipMemsetAsync(cur_a, 0, (NN + 1) * sizeof(int), stream);
  hist_k<<<(adj_nnz + 255) / 256, blk, 0, stream>>>(adj_rows, cur_a, adj_nnz);
  scan_block<<<nbN, blk, 0, stream>>>(cur_a, ptr_a, blks, NN + 1);
  scan_sums<<<1, 64, 0, stream>>>(blks, nbN);
  scan_add<<<nbN, blk, 0, stream>>>(ptr_a, cur_a, blks, NN + 1);
  scatter_k<<<(adj_nnz + 255) / 256, blk, 0, stream>>>(adj_rows, adj_cols, adj_vals, cur_a, pr_a, adj_nnz);

  // ---- build CSR: incT by inc_cols (rows = edges) ----
  hipMemsetAsync(cur_e, 0, (EN + 1) * sizeof(int), stream);
  hist_k<<<(inc_nnz + 255) / 256, blk, 0, stream>>>(inc_cols, cur_e, inc_nnz);
  scan_block<<<nbE, blk, 0, stream>>>(cur_e, ptr_e, blks, EN + 1);
  scan_sums<<<1, 64, 0, stream>>>(blks, nbE);
  scan_add<<<nbE, blk, 0, stream>>>(ptr_e, cur_e, blks, EN + 1);
  scatter_k<<<(inc_nnz + 255) / 256, blk, 0, stream>>>(inc_cols, inc_rows, inc_vals, cur_e, pr_e, inc_nnz);

  // ---- build CSR: inc by inc_rows (rows = nodes) ----
  hipMemsetAsync(cur_i, 0, (NN + 1) * sizeof(int), stream);
  hist_k<<<(inc_nnz + 255) / 256, blk, 0, stream>>>(inc_rows, cur_i, inc_nnz);
  scan_block<<<nbN, blk, 0, stream>>>(cur_i, ptr_i, blks, NN + 1);
  scan_sums<<<1, 64, 0, stream>>>(blks, nbN);
  scan_add<<<nbN, blk, 0, stream>>>(ptr_i, cur_i, blks, NN + 1);
  scatter_k<<<(inc_nnz + 255) / 256, blk, 0, stream>>>(inc_rows, inc_cols, inc_vals, cur_i, pr_i, inc_nnz);

  // ---- level 1 GEMMs (f32 x -> bf16 out) ----
  gemm_f32_b16<<<gN, dim3(128), 0, stream>>>(x, w00h, w00l, t1, NN);
  gemm_f32_b16<<<gN, dim3(128), 0, stream>>>(x, w01h, w01l, tA, NN);

  // ---- level 1 SpMMs (bf16 gather, fused sigmoid, bf16 out) ----
  csr_spmm_b16<true><<<(NN + 3) / 4, blk, 0, stream>>>(ptr_a, pr_a, (const unsigned*)t1, (unsigned*)n1, NN);
  csr_spmm_b16<true><<<(EN + 3) / 4, blk, 0, stream>>>(ptr_e, pr_e, (const unsigned*)tA, (unsigned*)e1, EN);

  // ---- level 2 GEMMs (bf16 in/out, in-place) ----
  gemm_b16_b16<<<gN, dim3(128), 0, stream>>>(n1, w20h, w20l, n1, NN);
  gemm_b16_b16<<<gE, dim3(128), 0, stream>>>(e1, w21h, w21l, e1, EN);

  // ---- fused level-2 SpMMs + merge sigmoid (f32 out) ----
  csr_spmm2_sig<<<(NN + 3) / 4, blk, 0, stream>>>(ptr_a, pr_a, (const unsigned*)n1,
                                                  ptr_i, pr_i, (const unsigned*)e1, outf, NN);
}